// Round 1
// baseline (328.689 us; speedup 1.0000x reference)
//
#include <hip/hip_runtime.h>
#include <hip/hip_bf16.h>
#include <stdint.h>

#define EPS 1e-6f
#define N_EMB 65536
#define K_CENT 1024
#define DIM 512

typedef __attribute__((ext_vector_type(8))) short short8;
typedef __attribute__((ext_vector_type(4))) float f32x4;

// ---------------- ws layout v6 (bytes) ----------------
// [0)         ck_term 1024 f                     (ends 4096)
// [4096)      en_term 65536 f                    (ends 266240)
// [266240)    Pk      up-to-8*65536 u64 (v7 uses 4 slices) (ends 4460544)
// [4460544)   E_bf16  65536*512 u16 = 64 MB      (ends 71569408)
// [71569408)  C_bf16  1024*512 u16 = 1 MB        (ends 72617984)
// [72617984)  gpart   32*3*1024 f = 384 KB       (ends 73011200)
// [73011200)  ticket  1 u32                      (ends 73011204)
#define WS6_BYTES 73011204ull

__device__ inline unsigned long long shflx64(unsigned long long v, int m) {
    int lo = __shfl_xor((int)(unsigned)(v & 0xffffffffull), m);
    int hi = __shfl_xor((int)(unsigned)(v >> 32), m);
    return ((unsigned long long)(unsigned)hi << 32) | (unsigned)lo;
}

__device__ inline unsigned pack_bf2(float x, float y) {
    __hip_bfloat162 h = __float22bfloat162_rn(make_float2(x, y));
    union { __hip_bfloat162 h; unsigned u; } c;
    c.h = h;
    return c.u;
}

__device__ inline uint4 pack_bf16x8(float4 a, float4 b) {
    uint4 r;
    r.x = pack_bf2(a.x, a.y);
    r.y = pack_bf2(a.z, a.w);
    r.z = pack_bf2(b.x, b.y);
    r.w = pack_bf2(b.z, b.w);
    return r;
}

// ---------------------------------------------------------------------------
// conv_v6: fp32->bf16 mirrors + row terms, 32 rows per block (8 per wave).
// ---------------------------------------------------------------------------
__global__ __launch_bounds__(256) void conv_v6_kernel(
    const float* __restrict__ E, const float* __restrict__ C,
    unsigned short* __restrict__ Eb, unsigned short* __restrict__ Cb,
    float* __restrict__ en_term, float* __restrict__ ck_term,
    unsigned int* __restrict__ ticket)
{
    const int wave = threadIdx.x >> 6;
    const int lane = threadIdx.x & 63;

    const float* X; unsigned short* Xb; float* term; float sa, c0; int row0;
    if (blockIdx.x < 32) {
        if (blockIdx.x == 0 && threadIdx.x == 0) *ticket = 0u;
        row0 = blockIdx.x * 32 + wave * 8;
        X = C; Xb = Cb; term = ck_term; sa = 2.0f * EPS; c0 = 0.0f;
    } else {
        row0 = (blockIdx.x - 32) * 32 + wave * 8;
        X = E; Xb = Eb; term = en_term; sa = -2.0f * EPS;
        c0 = (float)DIM * EPS * EPS;
    }

    #pragma unroll
    for (int r = 0; r < 8; r++) {
        const int row = row0 + r;
        const float* p = X + (size_t)row * DIM + lane * 8;
        float4 a = *(const float4*)(p);
        float4 b = *(const float4*)(p + 4);

        *(uint4*)&Xb[(size_t)row * DIM + lane * 8] = pack_bf16x8(a, b);

        float s  = a.x + a.y + a.z + a.w + b.x + b.y + b.z + b.w;
        float sq = a.x*a.x + a.y*a.y + a.z*a.z + a.w*a.w
                 + b.x*b.x + b.y*b.y + b.z*b.z + b.w*b.w;
        #pragma unroll
        for (int off = 32; off; off >>= 1) {
            s  += __shfl_down(s,  off);
            sq += __shfl_down(sq, off);
        }
        if (lane == 0) term[row] = sq + sa * s + c0;
    }
}

// ---------------------------------------------------------------------------
// mfma_assign_v7: 256 emb x 256 cent per block, 8 waves (2M x 4N), BK=32.
// 4-slot LDS ring buffer, 2-tile prefetch lead, ONE raw s_barrier per K-tile
// with counted s_waitcnt vmcnt(4) (T3+T4), setprio around MFMA cluster (T5).
// Swizzle: LDS slot = q ^ ((row>>1)&3) -> conflict-free ds_read_b128; inverse
// applied on pre-swizzled global source (global_load_lds dest stays linear).
// Per-pair MFMA chain identical to the verified v6 kernel -> bit-identical
// metrics/keys. Pk has 4 ct-slices. Grid 1024 = 256 et x 4 ct (ct fastest).
// ---------------------------------------------------------------------------
#define BM 256
#define BN 256
#define BKT 32
#define NTILE (DIM / BKT)   // 16

__global__ __launch_bounds__(512, 2) void mfma_assign_v7_kernel(
    const unsigned short* __restrict__ Eb, const unsigned short* __restrict__ Cb,
    const float* __restrict__ ck_term, unsigned long long* __restrict__ Pk)
{
    __shared__ unsigned short As[4][BM * BKT];        // 4 x 16 KB
    __shared__ unsigned short Bs[4][BN * BKT];        // 4 x 16 KB
    __shared__ unsigned long long red[BM][4];         // 8 KB  (136 KB total)

    const int tid  = threadIdx.x;
    const int lane = tid & 63;
    const int wave = tid >> 6;       // 0..7
    const int wm   = wave >> 2;      // 0..1 -> emb rows [wm*128, +128)
    const int wn   = wave & 3;       // 0..3 -> cent cols [wn*64, +64)
    const int quad = lane >> 4;      // 0..3
    const int col  = lane & 15;

    const int et = blockIdx.x >> 2;
    const int ct = blockIdx.x & 3;
    const int erow0 = et * BM;
    const int k0    = ct * BN;

    // staging lane decomposition: lane covers (row = half*16 + (lane>>2),
    // slot = lane&3); source k-group g = slot ^ f(row), f(row)=(row>>1)&3
    const int rsub = lane >> 2;                               // 0..15
    const int gsw  = ((lane & 3) ^ ((lane >> 3) & 3)) * 8;    // elems in row

    // read-side swizzled 16B-slot (elements); f(m) = (m>>1)&3 = (col>>1)&3
    const int fsw = (quad ^ ((col >> 1) & 3)) * 8;

    f32x4 acc[8][4];
    #pragma unroll
    for (int mi = 0; mi < 8; mi++)
        #pragma unroll
        for (int ni = 0; ni < 4; ni++)
            acc[mi][ni] = (f32x4){0.f, 0.f, 0.f, 0.f};

    // 4 global_load_lds instructions per thread per tile (A:2, B:2)
    auto stage = [&](int t) {
        const int dt = t * BKT;
        unsigned short* Ad = &As[t & 3][0];
        unsigned short* Bd = &Bs[t & 3][0];
        #pragma unroll
        for (int j = 0; j < 2; j++) {
            const int half = wave * 2 + j;            // 0..15
            const int row  = half * 16 + rsub;        // 0..255
            const unsigned short* ge =
                Eb + (size_t)(erow0 + row) * DIM + dt + gsw;
            __builtin_amdgcn_global_load_lds(
                (const __attribute__((address_space(1))) void*)ge,
                (__attribute__((address_space(3))) void*)(Ad + half * 512),
                16, 0, 0);
            const unsigned short* gc =
                Cb + (size_t)(k0 + row) * DIM + dt + gsw;
            __builtin_amdgcn_global_load_lds(
                (const __attribute__((address_space(1))) void*)gc,
                (__attribute__((address_space(3))) void*)(Bd + half * 512),
                16, 0, 0);
        }
    };

    // prologue: tiles 0 and 1 in flight (8 outstanding loads per wave)
    stage(0);
    stage(1);

    for (int t = 0; t < NTILE; t++) {
        // counted wait: my own tile-t loads are the oldest 4 of <=8 in flight
        if (t < NTILE - 1) { asm volatile("s_waitcnt vmcnt(4)" ::: "memory"); }
        else               { asm volatile("s_waitcnt vmcnt(0)" ::: "memory"); }
        __builtin_amdgcn_s_barrier();           // collective: buf[t&3] landed
        __builtin_amdgcn_sched_barrier(0);      // nothing crosses the barrier

        const int buf = t & 3;
        short8 afr[8], bfr[4];
        #pragma unroll
        for (int mi = 0; mi < 8; mi++) {
            const int m = wm * 128 + mi * 16 + col;
            afr[mi] = *(const short8*)&As[buf][m * BKT + fsw];
        }
        #pragma unroll
        for (int ni = 0; ni < 4; ni++) {
            const int n = wn * 64 + ni * 16 + col;
            bfr[ni] = *(const short8*)&Bs[buf][n * BKT + fsw];
        }

        // prefetch tile t+2 into buf (t+2)&3: last read in region t-2,
        // all waves past barrier(t) -> safe; lands before region t+2's wait.
        if (t < NTILE - 2) stage(t + 2);

        __builtin_amdgcn_s_setprio(1);
        #pragma unroll
        for (int mi = 0; mi < 8; mi++)
            #pragma unroll
            for (int ni = 0; ni < 4; ni++)
                acc[mi][ni] = __builtin_amdgcn_mfma_f32_16x16x32_bf16(
                    afr[mi], bfr[ni], acc[mi][ni], 0, 0, 0);
        __builtin_amdgcn_s_setprio(0);
    }
    __builtin_amdgcn_sched_barrier(0);

    // ---- argmin epilogue (identical key math to verified v6) ----
    float ck[4];
    #pragma unroll
    for (int ni = 0; ni < 4; ni++)
        ck[ni] = ck_term[k0 + wn * 64 + ni * 16 + col];

    #pragma unroll
    for (int mi = 0; mi < 8; mi++) {
        #pragma unroll
        for (int r = 0; r < 4; r++) {
            unsigned long long key = ~0ull;
            #pragma unroll
            for (int ni = 0; ni < 4; ni++) {
                float metric = fmaf(-2.0f, acc[mi][ni][r], ck[ni]);
                unsigned mb = __float_as_uint(metric);
                mb = (mb & 0x80000000u) ? ~mb : (mb | 0x80000000u);
                unsigned idx = (unsigned)(k0 + wn * 64 + ni * 16 + col);
                unsigned long long kk = ((unsigned long long)mb << 10) | idx;
                if (kk < key) key = kk;
            }
            #pragma unroll
            for (int s = 1; s < 16; s <<= 1) {
                unsigned long long o = shflx64(key, s);
                if (o < key) key = o;
            }
            if (col == 0) red[wm * 128 + mi * 16 + quad * 4 + r][wn] = key;
        }
    }
    __syncthreads();

    if (tid < BM) {
        unsigned long long a = red[tid][0];
        unsigned long long b = red[tid][1];
        unsigned long long c = red[tid][2];
        unsigned long long d = red[tid][3];
        unsigned long long m0 = a < b ? a : b;
        unsigned long long m1 = c < d ? c : d;
        Pk[(size_t)ct * N_EMB + erow0 + tid] = m0 < m1 ? m0 : m1;
    }
}

// ---------------------------------------------------------------------------
// reduce_finalize_v7: 32 blocks. Merge 4 Pk slices per emb, finish distance,
// per-block LDS partials, last-block election reduces 32 partials -> 3 outs.
// ---------------------------------------------------------------------------
#define RED_BLOCKS 32
__global__ __launch_bounds__(256) void reduce_finalize_v6_kernel(
    const unsigned long long* __restrict__ Pk, const float* __restrict__ en_term,
    float* __restrict__ gpart, unsigned int* __restrict__ ticket,
    float* __restrict__ out)
{
    __shared__ float cnt_s[K_CENT];
    __shared__ float sum_s[K_CENT];
    __shared__ unsigned max_s[K_CENT];

    const int tid = threadIdx.x;
    for (int k = tid; k < K_CENT; k += 256) {
        cnt_s[k] = 0.f; sum_s[k] = 0.f; max_s[k] = 0u;
    }
    __syncthreads();

    for (int i = blockIdx.x * 256 + tid; i < N_EMB; i += RED_BLOCKS * 256) {
        unsigned long long k = Pk[i];
        #pragma unroll
        for (int ct = 1; ct < 4; ct++) {
            unsigned long long o = Pk[(size_t)ct * N_EMB + i];
            if (o < k) k = o;
        }
        unsigned mb = (unsigned)(k >> 10);
        int idx = (int)(k & 1023u);
        unsigned b = (mb & 0x80000000u) ? (mb ^ 0x80000000u) : ~mb;
        float metric = __uint_as_float(b);
        float sq = metric + en_term[i];
        float dist = sqrtf(fmaxf(sq, 0.f));
        atomicAdd(&cnt_s[idx], 1.0f);
        atomicAdd(&sum_s[idx], dist);
        atomicMax(&max_s[idx], __float_as_uint(dist));
    }
    __syncthreads();

    float* gp = gpart + (size_t)blockIdx.x * 3 * K_CENT;
    for (int k = tid; k < K_CENT; k += 256) {
        __hip_atomic_store(&gp[k], cnt_s[k],
                           __ATOMIC_RELAXED, __HIP_MEMORY_SCOPE_AGENT);
        __hip_atomic_store(&gp[K_CENT + k], sum_s[k],
                           __ATOMIC_RELAXED, __HIP_MEMORY_SCOPE_AGENT);
        __hip_atomic_store(&gp[2 * K_CENT + k], __uint_as_float(max_s[k]),
                           __ATOMIC_RELAXED, __HIP_MEMORY_SCOPE_AGENT);
    }
    __threadfence();
    __syncthreads();

    __shared__ int lastf;
    if (tid == 0)
        lastf = (atomicAdd(ticket, 1u) == (unsigned)(RED_BLOCKS - 1));
    __syncthreads();
    if (!lastf) return;

    float a = 0.f, m = 0.f, c = 0.f;
    for (int k = tid; k < K_CENT; k += 256) {
        float cc = 0.f, ss = 0.f;
        unsigned mx = 0u;
        #pragma unroll 4
        for (int bb = 0; bb < RED_BLOCKS; bb++) {
            const float* gq = gpart + (size_t)bb * 3 * K_CENT;
            cc += __hip_atomic_load(&gq[k], __ATOMIC_RELAXED,
                                    __HIP_MEMORY_SCOPE_AGENT);
            ss += __hip_atomic_load(&gq[K_CENT + k], __ATOMIC_RELAXED,
                                    __HIP_MEMORY_SCOPE_AGENT);
            float mv = __hip_atomic_load(&gq[2 * K_CENT + k], __ATOMIC_RELAXED,
                                         __HIP_MEMORY_SCOPE_AGENT);
            unsigned mu = __float_as_uint(mv);
            if (mu > mx) mx = mu;
        }
        a += ss / (cc + 1.0f);
        m += __uint_as_float(mx);
        c += cc;
    }
    __shared__ float sa[4], sm[4], sc[4];
    #pragma unroll
    for (int off = 32; off; off >>= 1) {
        a += __shfl_down(a, off);
        m += __shfl_down(m, off);
        c += __shfl_down(c, off);
    }
    const int lane = tid & 63, w = tid >> 6;
    if (lane == 0) { sa[w] = a; sm[w] = m; sc[w] = c; }
    __syncthreads();
    if (tid == 0) {
        a = sa[0] + sa[1] + sa[2] + sa[3];
        m = sm[0] + sm[1] + sm[2] + sm[3];
        c = sc[0] + sc[1] + sc[2] + sc[3];
        out[0] = a / (float)K_CENT;
        out[1] = m / (float)K_CENT;
        out[2] = c / (float)K_CENT;
    }
}

// ---------------------------------------------------------------------------
// fp32 fallback path (round-1) if ws is too small.
// ---------------------------------------------------------------------------
__global__ __launch_bounds__(256) void row_stats_kernel(
    const float* __restrict__ X, float* __restrict__ term,
    float sa, float c0)
{
    const int wave = threadIdx.x >> 6;
    const int lane = threadIdx.x & 63;
    const int row  = blockIdx.x * 4 + wave;
    const float* p = X + (size_t)row * DIM;
    float4 a = *(const float4*)&p[lane * 4];
    float4 b = *(const float4*)&p[256 + lane * 4];
    float s  = a.x + a.y + a.z + a.w + b.x + b.y + b.z + b.w;
    float sq = a.x*a.x + a.y*a.y + a.z*a.z + a.w*a.w
             + b.x*b.x + b.y*b.y + b.z*b.z + b.w*b.w;
    #pragma unroll
    for (int off = 32; off; off >>= 1) {
        s  += __shfl_down(s,  off);
        sq += __shfl_down(sq, off);
    }
    if (lane == 0) term[row] = sq + sa * s + c0;
}

__global__ __launch_bounds__(256) void assign_kernel(
    const float* __restrict__ E, const float* __restrict__ C,
    const float* __restrict__ ck_term, const float* __restrict__ en_term,
    float* __restrict__ counts, float* __restrict__ sums,
    unsigned int* __restrict__ maxs)
{
    __shared__ float Es[16][64];
    __shared__ float Cs[16][64];
    __shared__ float red_sq[16][64];
    __shared__ int   red_idx[16][64];

    const int tid     = threadIdx.x;
    const int n0      = blockIdx.x * 64;
    const int en_base = (tid & 15) * 4;
    const int ck_base = (tid >> 4) * 4;
    const int tc      = tid >> 4;
    const int l_row = tid >> 2;
    const int l_col = (tid & 3) * 4;

    float et[4];
    #pragma unroll
    for (int i = 0; i < 4; i++) et[i] = en_term[n0 + en_base + i];
    float best[4];
    int   bidx[4];
    #pragma unroll
    for (int i = 0; i < 4; i++) { best[i] = 3.4e38f; bidx[i] = 0; }

    for (int kt = 0; kt < K_CENT; kt += 64) {
        float acc[4][4];
        #pragma unroll
        for (int i = 0; i < 4; i++)
            #pragma unroll
            for (int j = 0; j < 4; j++) acc[i][j] = 0.f;
        for (int dt = 0; dt < DIM; dt += 16) {
            __syncthreads();
            float4 ev = *(const float4*)&E[(size_t)(n0 + l_row) * DIM + dt + l_col];
            float4 cv = *(const float4*)&C[(size_t)(kt + l_row) * DIM + dt + l_col];
            Es[l_col + 0][l_row] = ev.x; Es[l_col + 1][l_row] = ev.y;
            Es[l_col + 2][l_row] = ev.z; Es[l_col + 3][l_row] = ev.w;
            Cs[l_col + 0][l_row] = cv.x; Cs[l_col + 1][l_row] = cv.y;
            Cs[l_col + 2][l_row] = cv.z; Cs[l_col + 3][l_row] = cv.w;
            __syncthreads();
            #pragma unroll
            for (int dd = 0; dd < 16; dd++) {
                float4 e4 = *(const float4*)&Es[dd][en_base];
                float4 c4 = *(const float4*)&Cs[dd][ck_base];
                float ee[4] = { e4.x, e4.y, e4.z, e4.w };
                float cc[4] = { c4.x, c4.y, c4.z, c4.w };
                #pragma unroll
                for (int i = 0; i < 4; i++)
                    #pragma unroll
                    for (int j = 0; j < 4; j++)
                        acc[i][j] = fmaf(ee[i], cc[j], acc[i][j]);
            }
        }
        #pragma unroll
        for (int j = 0; j < 4; j++) {
            float ckt = ck_term[kt + ck_base + j];
            int   kg  = kt + ck_base + j;
            #pragma unroll
            for (int i = 0; i < 4; i++) {
                float sqv = ckt + et[i] - 2.0f * acc[i][j];
                if (sqv < best[i]) { best[i] = sqv; bidx[i] = kg; }
            }
        }
    }
    #pragma unroll
    for (int i = 0; i < 4; i++) {
        red_sq[tc][en_base + i]  = best[i];
        red_idx[tc][en_base + i] = bidx[i];
    }
    __syncthreads();
    if (tid < 64) {
        float b  = red_sq[0][tid];
        int   bi = red_idx[0][tid];
        #pragma unroll
        for (int t = 1; t < 16; t++) {
            float v  = red_sq[t][tid];
            int   vi = red_idx[t][tid];
            if (v < b || (v == b && vi < bi)) { b = v; bi = vi; }
        }
        float dist = sqrtf(fmaxf(b, 0.f));
        atomicAdd(&counts[bi], 1.0f);
        atomicAdd(&sums[bi], dist);
        atomicMax(&maxs[bi], __float_as_uint(dist));
    }
}

__global__ __launch_bounds__(1024) void finalize_kernel(
    const float* __restrict__ counts, const float* __restrict__ sums,
    const float* __restrict__ maxs, float* __restrict__ out)
{
    const int k = threadIdx.x;
    float c = counts[k];
    float s = sums[k];
    float m = maxs[k];
    float a = s / (c + 1.0f);
    __shared__ float sa[16], sm[16], sc[16];
    #pragma unroll
    for (int off = 32; off; off >>= 1) {
        a += __shfl_down(a, off);
        m += __shfl_down(m, off);
        c += __shfl_down(c, off);
    }
    const int lane = k & 63, w = k >> 6;
    if (lane == 0) { sa[w] = a; sm[w] = m; sc[w] = c; }
    __syncthreads();
    if (k < 64) {
        a = (k < 16) ? sa[k] : 0.f;
        m = (k < 16) ? sm[k] : 0.f;
        c = (k < 16) ? sc[k] : 0.f;
        #pragma unroll
        for (int off = 8; off; off >>= 1) {
            a += __shfl_down(a, off);
            m += __shfl_down(m, off);
            c += __shfl_down(c, off);
        }
        if (k == 0) {
            out[0] = a / (float)K_CENT;
            out[1] = m / (float)K_CENT;
            out[2] = c / (float)K_CENT;
        }
    }
}

extern "C" void kernel_launch(void* const* d_in, const int* in_sizes, int n_in,
                              void* d_out, int out_size, void* d_ws, size_t ws_size,
                              hipStream_t stream) {
    const float* E = (const float*)d_in[0];   // (65536, 512)
    const float* C = (const float*)d_in[1];   // (1024, 512)

    char* wsb = (char*)d_ws;

    if (ws_size >= WS6_BYTES) {
        float* ck_term         = (float*)(wsb + 0);
        float* en_term         = (float*)(wsb + 4096);
        unsigned long long* Pk = (unsigned long long*)(wsb + 266240);
        unsigned short* Eb     = (unsigned short*)(wsb + 4460544);
        unsigned short* Cb     = (unsigned short*)(wsb + 71569408);
        float* gpart           = (float*)(wsb + 72617984);
        unsigned int* ticket   = (unsigned int*)(wsb + 73011200);

        conv_v6_kernel<<<32 + N_EMB / 32, 256, 0, stream>>>(
            E, C, Eb, Cb, en_term, ck_term, ticket);
        mfma_assign_v7_kernel<<<(N_EMB / BM) * (K_CENT / BN), 512, 0, stream>>>(
            Eb, Cb, ck_term, Pk);
        reduce_finalize_v6_kernel<<<RED_BLOCKS, 256, 0, stream>>>(
            Pk, en_term, gpart, ticket, (float*)d_out);
    } else {
        float* counts  = (float*)(wsb + 0);
        float* sums    = (float*)(wsb + 4096);
        float* maxs    = (float*)(wsb + 8192);
        float* ck_term = (float*)(wsb + 12288);
        float* en_term = (float*)(wsb + 16384);
        hipMemsetAsync(counts, 0, 3 * K_CENT * sizeof(float), stream);
        row_stats_kernel<<<K_CENT / 4, 256, 0, stream>>>(
            C, ck_term, 2.0f * EPS, 0.0f);
        row_stats_kernel<<<N_EMB / 4, 256, 0, stream>>>(
            E, en_term, -2.0f * EPS, (float)DIM * EPS * EPS);
        assign_kernel<<<N_EMB / 64, 256, 0, stream>>>(
            E, C, ck_term, en_term, counts, sums, (unsigned int*)maxs);
        finalize_kernel<<<1, 1024, 0, stream>>>(counts, sums, maxs, (float*)d_out);
    }
}

// Round 2
// 319.444 us; speedup vs baseline: 1.0289x; 1.0289x over previous
//
#include <hip/hip_runtime.h>
#include <hip/hip_bf16.h>
#include <stdint.h>

#define EPS 1e-6f
#define N_EMB 65536
#define K_CENT 1024
#define DIM 512

typedef __attribute__((ext_vector_type(8))) short short8;
typedef __attribute__((ext_vector_type(4))) float f32x4;

// ---------------- ws layout v6 (bytes) ----------------
// [0)         ck_term 1024 f                     (ends 4096)
// [4096)      en_term 65536 f                    (ends 266240)
// [266240)    Pk      up-to-8*65536 u64 (v8 uses 4 slices) (ends 4460544)
// [4460544)   E_bf16  65536*512 u16 = 64 MB      (ends 71569408)
// [71569408)  C_bf16  1024*512 u16 = 1 MB        (ends 72617984)
// [72617984)  gpart   32*3*1024 f = 384 KB       (ends 73011200)
// [73011200)  ticket  1 u32                      (ends 73011204)
#define WS6_BYTES 73011204ull

__device__ inline unsigned long long shflx64(unsigned long long v, int m) {
    int lo = __shfl_xor((int)(unsigned)(v & 0xffffffffull), m);
    int hi = __shfl_xor((int)(unsigned)(v >> 32), m);
    return ((unsigned long long)(unsigned)hi << 32) | (unsigned)lo;
}

__device__ inline unsigned pack_bf2(float x, float y) {
    __hip_bfloat162 h = __float22bfloat162_rn(make_float2(x, y));
    union { __hip_bfloat162 h; unsigned u; } c;
    c.h = h;
    return c.u;
}

__device__ inline uint4 pack_bf16x8(float4 a, float4 b) {
    uint4 r;
    r.x = pack_bf2(a.x, a.y);
    r.y = pack_bf2(a.z, a.w);
    r.z = pack_bf2(b.x, b.y);
    r.w = pack_bf2(b.z, b.w);
    return r;
}

// ---------------------------------------------------------------------------
// conv_v6: fp32->bf16 mirrors + row terms, 32 rows per block (8 per wave).
// ---------------------------------------------------------------------------
__global__ __launch_bounds__(256) void conv_v6_kernel(
    const float* __restrict__ E, const float* __restrict__ C,
    unsigned short* __restrict__ Eb, unsigned short* __restrict__ Cb,
    float* __restrict__ en_term, float* __restrict__ ck_term,
    unsigned int* __restrict__ ticket)
{
    const int wave = threadIdx.x >> 6;
    const int lane = threadIdx.x & 63;

    const float* X; unsigned short* Xb; float* term; float sa, c0; int row0;
    if (blockIdx.x < 32) {
        if (blockIdx.x == 0 && threadIdx.x == 0) *ticket = 0u;
        row0 = blockIdx.x * 32 + wave * 8;
        X = C; Xb = Cb; term = ck_term; sa = 2.0f * EPS; c0 = 0.0f;
    } else {
        row0 = (blockIdx.x - 32) * 32 + wave * 8;
        X = E; Xb = Eb; term = en_term; sa = -2.0f * EPS;
        c0 = (float)DIM * EPS * EPS;
    }

    #pragma unroll
    for (int r = 0; r < 8; r++) {
        const int row = row0 + r;
        const float* p = X + (size_t)row * DIM + lane * 8;
        float4 a = *(const float4*)(p);
        float4 b = *(const float4*)(p + 4);

        *(uint4*)&Xb[(size_t)row * DIM + lane * 8] = pack_bf16x8(a, b);

        float s  = a.x + a.y + a.z + a.w + b.x + b.y + b.z + b.w;
        float sq = a.x*a.x + a.y*a.y + a.z*a.z + a.w*a.w
                 + b.x*b.x + b.y*b.y + b.z*b.z + b.w*b.w;
        #pragma unroll
        for (int off = 32; off; off >>= 1) {
            s  += __shfl_down(s,  off);
            sq += __shfl_down(sq, off);
        }
        if (lane == 0) term[row] = sq + sa * s + c0;
    }
}

// ---------------------------------------------------------------------------
// mfma_assign_v8: m201-style 8-phase schedule. 256x256 tile, 8 waves (2Mx4N),
// BK=64, 8 K-steps, 4 phases/K-step. Per phase: ds_read one operand quadrant,
// issue ONE 16KB stage unit (2 gload_lds/thread), 1 barrier, 16 MFMA in
// setprio(1). vmcnt(2) only at phases 0/1 of each K-step (counted, no drain).
// Stage units match read quadrants: A-mq = rows {mq*64..+64} of both wm
// halves; B-nh = cols (n&63)<32 / >=32 across all wn groups. Swizzle:
// read slot = (ks*4+quad)^(col&7); source pre-swizzled (lane&7)^(u&7).
// K-accum order identical to v6/v7 -> bit-identical keys. Pk: 4 ct-slices.
// ---------------------------------------------------------------------------
#define BM 256
#define BN 256
#define BK 64
#define NK (DIM / BK)   // 8

__global__ __launch_bounds__(512, 2) void mfma_assign_v8_kernel(
    const unsigned short* __restrict__ Eb, const unsigned short* __restrict__ Cb,
    const float* __restrict__ ck_term, unsigned long long* __restrict__ Pk)
{
    // A: [2 buf][2 mq][2 wm][64 rows][64 elems]  = 2 x 32 KB
    // B: [2 buf][2 nh][4 wn][32 rows][64 elems]  = 2 x 32 KB
    __shared__ unsigned short As[2 * 16384];
    __shared__ unsigned short Bs[2 * 16384];
    __shared__ unsigned long long red[BM][4];

    const int tid  = threadIdx.x;
    const int lane = tid & 63;
    const int wave = tid >> 6;       // 0..7
    const int wm   = wave >> 2;      // 0..1
    const int wn   = wave & 3;       // 0..3
    const int quad = lane >> 4;      // 0..3
    const int col  = lane & 15;

    const unsigned bid = blockIdx.x;
    const unsigned wg  = (bid & 7u) * 128u + (bid >> 3);   // XCD swizzle, bijective (1024%8==0)
    const int et = (int)(wg >> 2);
    const int ct = (int)(wg & 3);
    const int erow0 = et * BM;
    const int k0    = ct * BN;

    // staging precompute: unit row u, pre-swizzled source slot, linear dest
    int u0_[2], sg_[2], du_[2];
    #pragma unroll
    for (int j = 0; j < 2; j++) {
        const int u = (wave * 2 + j) * 8 + (lane >> 3);    // 0..127
        u0_[j] = u;
        sg_[j] = ((lane & 7) ^ (u & 7)) * 8;               // source elem offset
        du_[j] = (wave * 2 + j) * 512 + lane * 8;          // dest elem offset in 16KB unit
    }

    auto stageA = [&](int kt, int mq) {
        const int buf = kt & 1;
        #pragma unroll
        for (int j = 0; j < 2; j++) {
            const int u = u0_[j];
            const int row = erow0 + (u >> 6) * 128 + mq * 64 + (u & 63);
            const unsigned short* src = Eb + (size_t)row * DIM + kt * BK + sg_[j];
            __builtin_amdgcn_global_load_lds(
                (const __attribute__((address_space(1))) void*)src,
                (__attribute__((address_space(3))) void*)
                    (As + buf * 16384 + mq * 8192 + du_[j]),
                16, 0, 0);
        }
    };
    auto stageB = [&](int kt, int nh) {
        const int buf = kt & 1;
        #pragma unroll
        for (int j = 0; j < 2; j++) {
            const int u = u0_[j];
            const int row = k0 + (u >> 5) * 64 + nh * 32 + (u & 31);
            const unsigned short* src = Cb + (size_t)row * DIM + kt * BK + sg_[j];
            __builtin_amdgcn_global_load_lds(
                (const __attribute__((address_space(1))) void*)src,
                (__attribute__((address_space(3))) void*)
                    (Bs + buf * 16384 + nh * 8192 + du_[j]),
                16, 0, 0);
        }
    };

    f32x4 acc[8][4];
    #pragma unroll
    for (int mi = 0; mi < 8; mi++)
        #pragma unroll
        for (int ni = 0; ni < 4; ni++)
            acc[mi][ni] = (f32x4){0.f, 0.f, 0.f, 0.f};

    short8 afr[4][2], bfr[2][2];

    auto LDA = [&](int buf, int mq) {
        #pragma unroll
        for (int a = 0; a < 4; a++)
            #pragma unroll
            for (int ks = 0; ks < 2; ks++) {
                const int mrow = a * 16 + col;
                const int slot = (ks * 4 + quad) ^ (col & 7);
                afr[a][ks] = *(const short8*)&As[buf * 16384 + mq * 8192
                                                + wm * 4096 + mrow * 64 + slot * 8];
            }
    };
    auto LDB = [&](int buf, int nh) {
        #pragma unroll
        for (int b = 0; b < 2; b++)
            #pragma unroll
            for (int ks = 0; ks < 2; ks++) {
                const int brow = b * 16 + col;
                const int slot = (ks * 4 + quad) ^ (col & 7);
                bfr[b][ks] = *(const short8*)&Bs[buf * 16384 + nh * 8192
                                                + wn * 2048 + brow * 64 + slot * 8];
            }
    };
    auto MM = [&](int mq, int nh) {
        __builtin_amdgcn_s_setprio(1);
        #pragma unroll
        for (int a = 0; a < 4; a++)
            #pragma unroll
            for (int b = 0; b < 2; b++) {
                const int mi = mq * 4 + a;
                const int ni = nh * 2 + b;
                acc[mi][ni] = __builtin_amdgcn_mfma_f32_16x16x32_bf16(
                    afr[a][0], bfr[b][0], acc[mi][ni], 0, 0, 0);
                acc[mi][ni] = __builtin_amdgcn_mfma_f32_16x16x32_bf16(
                    afr[a][1], bfr[b][1], acc[mi][ni], 0, 0, 0);
            }
        __builtin_amdgcn_s_setprio(0);
    };

    // prologue: K-step 0's 4 units, in the steady-state order
    stageA(0, 0);
    stageA(0, 1);
    stageB(0, 0);
    stageB(0, 1);

    for (int t = 0; t < NK; t++) {
        const int buf = t & 1;
        const bool st = (t < NK - 1);

        // ---- phase 0: Q(mq0, nh0) ----
        asm volatile("s_waitcnt vmcnt(2)" ::: "memory");
        __builtin_amdgcn_s_barrier();
        __builtin_amdgcn_sched_barrier(0);
        LDA(buf, 0);
        LDB(buf, 0);
        if (st) stageA(t + 1, 0);
        MM(0, 0);

        // ---- phase 1: Q(mq0, nh1) ----
        if (st) { asm volatile("s_waitcnt vmcnt(2)" ::: "memory"); }
        else    { asm volatile("s_waitcnt vmcnt(0)" ::: "memory"); }
        __builtin_amdgcn_s_barrier();
        __builtin_amdgcn_sched_barrier(0);
        LDB(buf, 1);
        if (st) stageA(t + 1, 1);
        MM(0, 1);

        // ---- phase 2: Q(mq1, nh1) ----
        __builtin_amdgcn_s_barrier();
        __builtin_amdgcn_sched_barrier(0);
        LDA(buf, 1);
        if (st) stageB(t + 1, 0);
        MM(1, 1);

        // ---- phase 3: Q(mq1, nh0) ----
        __builtin_amdgcn_s_barrier();
        __builtin_amdgcn_sched_barrier(0);
        LDB(buf, 0);
        if (st) stageB(t + 1, 1);
        MM(1, 0);
    }
    __builtin_amdgcn_sched_barrier(0);

    // ---- argmin epilogue (identical key math to verified v6/v7) ----
    float ck[4];
    #pragma unroll
    for (int ni = 0; ni < 4; ni++)
        ck[ni] = ck_term[k0 + wn * 64 + ni * 16 + col];

    #pragma unroll
    for (int mi = 0; mi < 8; mi++) {
        #pragma unroll
        for (int r = 0; r < 4; r++) {
            unsigned long long key = ~0ull;
            #pragma unroll
            for (int ni = 0; ni < 4; ni++) {
                float metric = fmaf(-2.0f, acc[mi][ni][r], ck[ni]);
                unsigned mb = __float_as_uint(metric);
                mb = (mb & 0x80000000u) ? ~mb : (mb | 0x80000000u);
                unsigned idx = (unsigned)(k0 + wn * 64 + ni * 16 + col);
                unsigned long long kk = ((unsigned long long)mb << 10) | idx;
                if (kk < key) key = kk;
            }
            #pragma unroll
            for (int s = 1; s < 16; s <<= 1) {
                unsigned long long o = shflx64(key, s);
                if (o < key) key = o;
            }
            if (col == 0) red[wm * 128 + mi * 16 + quad * 4 + r][wn] = key;
        }
    }
    __syncthreads();

    if (tid < BM) {
        unsigned long long a = red[tid][0];
        unsigned long long b = red[tid][1];
        unsigned long long c = red[tid][2];
        unsigned long long d = red[tid][3];
        unsigned long long m0 = a < b ? a : b;
        unsigned long long m1 = c < d ? c : d;
        Pk[(size_t)ct * N_EMB + erow0 + tid] = m0 < m1 ? m0 : m1;
    }
}

// ---------------------------------------------------------------------------
// reduce_finalize: 32 blocks. Merge 4 Pk slices per emb, finish distance,
// per-block LDS partials, last-block election reduces 32 partials -> 3 outs.
// ---------------------------------------------------------------------------
#define RED_BLOCKS 32
__global__ __launch_bounds__(256) void reduce_finalize_v6_kernel(
    const unsigned long long* __restrict__ Pk, const float* __restrict__ en_term,
    float* __restrict__ gpart, unsigned int* __restrict__ ticket,
    float* __restrict__ out)
{
    __shared__ float cnt_s[K_CENT];
    __shared__ float sum_s[K_CENT];
    __shared__ unsigned max_s[K_CENT];

    const int tid = threadIdx.x;
    for (int k = tid; k < K_CENT; k += 256) {
        cnt_s[k] = 0.f; sum_s[k] = 0.f; max_s[k] = 0u;
    }
    __syncthreads();

    for (int i = blockIdx.x * 256 + tid; i < N_EMB; i += RED_BLOCKS * 256) {
        unsigned long long k = Pk[i];
        #pragma unroll
        for (int ct = 1; ct < 4; ct++) {
            unsigned long long o = Pk[(size_t)ct * N_EMB + i];
            if (o < k) k = o;
        }
        unsigned mb = (unsigned)(k >> 10);
        int idx = (int)(k & 1023u);
        unsigned b = (mb & 0x80000000u) ? (mb ^ 0x80000000u) : ~mb;
        float metric = __uint_as_float(b);
        float sq = metric + en_term[i];
        float dist = sqrtf(fmaxf(sq, 0.f));
        atomicAdd(&cnt_s[idx], 1.0f);
        atomicAdd(&sum_s[idx], dist);
        atomicMax(&max_s[idx], __float_as_uint(dist));
    }
    __syncthreads();

    float* gp = gpart + (size_t)blockIdx.x * 3 * K_CENT;
    for (int k = tid; k < K_CENT; k += 256) {
        __hip_atomic_store(&gp[k], cnt_s[k],
                           __ATOMIC_RELAXED, __HIP_MEMORY_SCOPE_AGENT);
        __hip_atomic_store(&gp[K_CENT + k], sum_s[k],
                           __ATOMIC_RELAXED, __HIP_MEMORY_SCOPE_AGENT);
        __hip_atomic_store(&gp[2 * K_CENT + k], __uint_as_float(max_s[k]),
                           __ATOMIC_RELAXED, __HIP_MEMORY_SCOPE_AGENT);
    }
    __threadfence();
    __syncthreads();

    __shared__ int lastf;
    if (tid == 0)
        lastf = (atomicAdd(ticket, 1u) == (unsigned)(RED_BLOCKS - 1));
    __syncthreads();
    if (!lastf) return;

    float a = 0.f, m = 0.f, c = 0.f;
    for (int k = tid; k < K_CENT; k += 256) {
        float cc = 0.f, ss = 0.f;
        unsigned mx = 0u;
        #pragma unroll 4
        for (int bb = 0; bb < RED_BLOCKS; bb++) {
            const float* gq = gpart + (size_t)bb * 3 * K_CENT;
            cc += __hip_atomic_load(&gq[k], __ATOMIC_RELAXED,
                                    __HIP_MEMORY_SCOPE_AGENT);
            ss += __hip_atomic_load(&gq[K_CENT + k], __ATOMIC_RELAXED,
                                    __HIP_MEMORY_SCOPE_AGENT);
            float mv = __hip_atomic_load(&gq[2 * K_CENT + k], __ATOMIC_RELAXED,
                                         __HIP_MEMORY_SCOPE_AGENT);
            unsigned mu = __float_as_uint(mv);
            if (mu > mx) mx = mu;
        }
        a += ss / (cc + 1.0f);
        m += __uint_as_float(mx);
        c += cc;
    }
    __shared__ float sa[4], sm[4], sc[4];
    #pragma unroll
    for (int off = 32; off; off >>= 1) {
        a += __shfl_down(a, off);
        m += __shfl_down(m, off);
        c += __shfl_down(c, off);
    }
    const int lane = tid & 63, w = tid >> 6;
    if (lane == 0) { sa[w] = a; sm[w] = m; sc[w] = c; }
    __syncthreads();
    if (tid == 0) {
        a = sa[0] + sa[1] + sa[2] + sa[3];
        m = sm[0] + sm[1] + sm[2] + sm[3];
        c = sc[0] + sc[1] + sc[2] + sc[3];
        out[0] = a / (float)K_CENT;
        out[1] = m / (float)K_CENT;
        out[2] = c / (float)K_CENT;
    }
}

// ---------------------------------------------------------------------------
// fp32 fallback path (round-1) if ws is too small.
// ---------------------------------------------------------------------------
__global__ __launch_bounds__(256) void row_stats_kernel(
    const float* __restrict__ X, float* __restrict__ term,
    float sa, float c0)
{
    const int wave = threadIdx.x >> 6;
    const int lane = threadIdx.x & 63;
    const int row  = blockIdx.x * 4 + wave;
    const float* p = X + (size_t)row * DIM;
    float4 a = *(const float4*)&p[lane * 4];
    float4 b = *(const float4*)&p[256 + lane * 4];
    float s  = a.x + a.y + a.z + a.w + b.x + b.y + b.z + b.w;
    float sq = a.x*a.x + a.y*a.y + a.z*a.z + a.w*a.w
             + b.x*b.x + b.y*b.y + b.z*b.z + b.w*b.w;
    #pragma unroll
    for (int off = 32; off; off >>= 1) {
        s  += __shfl_down(s,  off);
        sq += __shfl_down(sq, off);
    }
    if (lane == 0) term[row] = sq + sa * s + c0;
}

__global__ __launch_bounds__(256) void assign_kernel(
    const float* __restrict__ E, const float* __restrict__ C,
    const float* __restrict__ ck_term, const float* __restrict__ en_term,
    float* __restrict__ counts, float* __restrict__ sums,
    unsigned int* __restrict__ maxs)
{
    __shared__ float Es[16][64];
    __shared__ float Cs[16][64];
    __shared__ float red_sq[16][64];
    __shared__ int   red_idx[16][64];

    const int tid     = threadIdx.x;
    const int n0      = blockIdx.x * 64;
    const int en_base = (tid & 15) * 4;
    const int ck_base = (tid >> 4) * 4;
    const int tc      = tid >> 4;
    const int l_row = tid >> 2;
    const int l_col = (tid & 3) * 4;

    float et[4];
    #pragma unroll
    for (int i = 0; i < 4; i++) et[i] = en_term[n0 + en_base + i];
    float best[4];
    int   bidx[4];
    #pragma unroll
    for (int i = 0; i < 4; i++) { best[i] = 3.4e38f; bidx[i] = 0; }

    for (int kt = 0; kt < K_CENT; kt += 64) {
        float acc[4][4];
        #pragma unroll
        for (int i = 0; i < 4; i++)
            #pragma unroll
            for (int j = 0; j < 4; j++) acc[i][j] = 0.f;
        for (int dt = 0; dt < DIM; dt += 16) {
            __syncthreads();
            float4 ev = *(const float4*)&E[(size_t)(n0 + l_row) * DIM + dt + l_col];
            float4 cv = *(const float4*)&C[(size_t)(kt + l_row) * DIM + dt + l_col];
            Es[l_col + 0][l_row] = ev.x; Es[l_col + 1][l_row] = ev.y;
            Es[l_col + 2][l_row] = ev.z; Es[l_col + 3][l_row] = ev.w;
            Cs[l_col + 0][l_row] = cv.x; Cs[l_col + 1][l_row] = cv.y;
            Cs[l_col + 2][l_row] = cv.z; Cs[l_col + 3][l_row] = cv.w;
            __syncthreads();
            #pragma unroll
            for (int dd = 0; dd < 16; dd++) {
                float4 e4 = *(const float4*)&Es[dd][en_base];
                float4 c4 = *(const float4*)&Cs[dd][ck_base];
                float ee[4] = { e4.x, e4.y, e4.z, e4.w };
                float cc[4] = { c4.x, c4.y, c4.z, c4.w };
                #pragma unroll
                for (int i = 0; i < 4; i++)
                    #pragma unroll
                    for (int j = 0; j < 4; j++)
                        acc[i][j] = fmaf(ee[i], cc[j], acc[i][j]);
            }
        }
        #pragma unroll
        for (int j = 0; j < 4; j++) {
            float ckt = ck_term[kt + ck_base + j];
            int   kg  = kt + ck_base + j;
            #pragma unroll
            for (int i = 0; i < 4; i++) {
                float sqv = ckt + et[i] - 2.0f * acc[i][j];
                if (sqv < best[i]) { best[i] = sqv; bidx[i] = kg; }
            }
        }
    }
    #pragma unroll
    for (int i = 0; i < 4; i++) {
        red_sq[tc][en_base + i]  = best[i];
        red_idx[tc][en_base + i] = bidx[i];
    }
    __syncthreads();
    if (tid < 64) {
        float b  = red_sq[0][tid];
        int   bi = red_idx[0][tid];
        #pragma unroll
        for (int t = 1; t < 16; t++) {
            float v  = red_sq[t][tid];
            int   vi = red_idx[t][tid];
            if (v < b || (v == b && vi < bi)) { b = v; bi = vi; }
        }
        float dist = sqrtf(fmaxf(b, 0.f));
        atomicAdd(&counts[bi], 1.0f);
        atomicAdd(&sums[bi], dist);
        atomicMax(&maxs[bi], __float_as_uint(dist));
    }
}

__global__ __launch_bounds__(1024) void finalize_kernel(
    const float* __restrict__ counts, const float* __restrict__ sums,
    const float* __restrict__ maxs, float* __restrict__ out)
{
    const int k = threadIdx.x;
    float c = counts[k];
    float s = sums[k];
    float m = maxs[k];
    float a = s / (c + 1.0f);
    __shared__ float sa[16], sm[16], sc[16];
    #pragma unroll
    for (int off = 32; off; off >>= 1) {
        a += __shfl_down(a, off);
        m += __shfl_down(m, off);
        c += __shfl_down(c, off);
    }
    const int lane = k & 63, w = k >> 6;
    if (lane == 0) { sa[w] = a; sm[w] = m; sc[w] = c; }
    __syncthreads();
    if (k < 64) {
        a = (k < 16) ? sa[k] : 0.f;
        m = (k < 16) ? sm[k] : 0.f;
        c = (k < 16) ? sc[k] : 0.f;
        #pragma unroll
        for (int off = 8; off; off >>= 1) {
            a += __shfl_down(a, off);
            m += __shfl_down(m, off);
            c += __shfl_down(c, off);
        }
        if (k == 0) {
            out[0] = a / (float)K_CENT;
            out[1] = m / (float)K_CENT;
            out[2] = c / (float)K_CENT;
        }
    }
}

extern "C" void kernel_launch(void* const* d_in, const int* in_sizes, int n_in,
                              void* d_out, int out_size, void* d_ws, size_t ws_size,
                              hipStream_t stream) {
    const float* E = (const float*)d_in[0];   // (65536, 512)
    const float* C = (const float*)d_in[1];   // (1024, 512)

    char* wsb = (char*)d_ws;

    if (ws_size >= WS6_BYTES) {
        float* ck_term         = (float*)(wsb + 0);
        float* en_term         = (float*)(wsb + 4096);
        unsigned long long* Pk = (unsigned long long*)(wsb + 266240);
        unsigned short* Eb     = (unsigned short*)(wsb + 4460544);
        unsigned short* Cb     = (unsigned short*)(wsb + 71569408);
        float* gpart           = (float*)(wsb + 72617984);
        unsigned int* ticket   = (unsigned int*)(wsb + 73011200);

        conv_v6_kernel<<<32 + N_EMB / 32, 256, 0, stream>>>(
            E, C, Eb, Cb, en_term, ck_term, ticket);
        mfma_assign_v8_kernel<<<(N_EMB / BM) * (K_CENT / BN), 512, 0, stream>>>(
            Eb, Cb, ck_term, Pk);
        reduce_finalize_v6_kernel<<<RED_BLOCKS, 256, 0, stream>>>(
            Pk, en_term, gpart, ticket, (float*)d_out);
    } else {
        float* counts  = (float*)(wsb + 0);
        float* sums    = (float*)(wsb + 4096);
        float* maxs    = (float*)(wsb + 8192);
        float* ck_term = (float*)(wsb + 12288);
        float* en_term = (float*)(wsb + 16384);
        hipMemsetAsync(counts, 0, 3 * K_CENT * sizeof(float), stream);
        row_stats_kernel<<<K_CENT / 4, 256, 0, stream>>>(
            C, ck_term, 2.0f * EPS, 0.0f);
        row_stats_kernel<<<N_EMB / 4, 256, 0, stream>>>(
            E, en_term, -2.0f * EPS, (float)DIM * EPS * EPS);
        assign_kernel<<<N_EMB / 64, 256, 0, stream>>>(
            E, C, ck_term, en_term, counts, sums, (unsigned int*)maxs);
        finalize_kernel<<<1, 1024, 0, stream>>>(counts, sums, maxs, (float*)d_out);
    }
}